// Round 4
// baseline (517.501 us; speedup 1.0000x reference)
//
#include <hip/hip_runtime.h>
#include <hip/hip_bf16.h>
#include <stdint.h>

#define N_NODES 25000
#define M_PAD   25088          // 196 * 128
#define E_EDGES 400000
#define NE      (E_EDGES + N_NODES)   // 425000 (edges + self loops)
#define HEADS   4
#define D_DIM   1024           // H*C = D_IN = 1024
#define NEG_SLOPE 0.2f
#define NBLK_SCAN ((N_NODES + 255) / 256)   // 98

using bf16x8  = __attribute__((ext_vector_type(8))) short;
using floatx4 = __attribute__((ext_vector_type(4))) float;
using ushort8 = __attribute__((ext_vector_type(8))) unsigned short;
typedef float  f32x4v __attribute__((ext_vector_type(4)));

__device__ __forceinline__ unsigned short f2bf(float f) {
    union { float f; unsigned u; } v{f};
    unsigned r = v.u + 0x7fffu + ((v.u >> 16) & 1u);   // round-to-nearest-even
    return (unsigned short)(r >> 16);
}
__device__ __forceinline__ float bf2f(unsigned short s) {
    union { unsigned u; float f; } v{(unsigned)s << 16};
    return v.f;
}

// ---------------- convert x (fp32 -> bf16, zero-pad rows to M_PAD) ----------
__global__ __launch_bounds__(256) void k_convert_x(
        const float* __restrict__ x, unsigned short* __restrict__ xb) {
    int i = blockIdx.x * 256 + threadIdx.x;          // quad index
    int row = i >> 8;                                // 256 quads per row
    if (row >= M_PAD) return;
    ushort4 o;
    if (row < N_NODES) {
        f32x4v v = __builtin_nontemporal_load((const f32x4v*)x + i);
        o = make_ushort4(f2bf(v.x), f2bf(v.y), f2bf(v.z), f2bf(v.w));
    } else {
        o = make_ushort4(0, 0, 0, 0);
    }
    ((ushort4*)xb)[i] = o;
}

// ---------------- convert W (fp32 [K][N] -> bf16 transposed [N][K]) ---------
__global__ void k_convert_wt(const float* __restrict__ W,
                             unsigned short* __restrict__ Wt) {
    __shared__ float tile[32][33];
    int bx = blockIdx.x, by = blockIdx.y;
    int tx = threadIdx.x, ty = threadIdx.y;          // 32 x 8
    #pragma unroll
    for (int i = 0; i < 32; i += 8) {
        int k = by * 32 + ty + i;
        int n = bx * 32 + tx;
        tile[ty + i][tx] = W[(size_t)k * D_DIM + n];
    }
    __syncthreads();
    #pragma unroll
    for (int i = 0; i < 32; i += 8) {
        int n = bx * 32 + ty + i;
        int k = by * 32 + tx;
        Wt[(size_t)n * D_DIM + k] = f2bf(tile[tx][ty + i]);
    }
}

// ---------------- GEMM: xp = x @ W  + fused per-node logit partials ---------
// bf16 MFMA 128x128 tile, BK=32, global_load_lds staging (m97 pattern).
// Epilogue: partial dot(acc_row_chunk, att_{src,dst}_chunk) -> 16-lane shfl
// reduce -> atomicAdd into a_src/a_dst[row][head]. Block's 128 cols lie in
// one head iff spanning 128 aligned cols (always: head width 256).
__global__ __launch_bounds__(256) void k_gemm(
        const unsigned short* __restrict__ A,
        const unsigned short* __restrict__ Bt,
        unsigned short* __restrict__ C,
        const float* __restrict__ att_src, const float* __restrict__ att_dst,
        float* __restrict__ a_src, float* __restrict__ a_dst) {
    __shared__ __align__(16) unsigned short As[128 * 32];
    __shared__ __align__(16) unsigned short Bs[128 * 32];

    const int tid  = threadIdx.x;
    const int m0   = blockIdx.x * 128;
    const int n0   = blockIdx.y * 128;
    const int wave = tid >> 6, lane = tid & 63;
    const int wm   = (wave & 1) * 64, wn = (wave >> 1) * 64;
    const int lrow = lane & 15;
    const int quad = lane >> 4;

    const int srow = (lane >> 2);        // 0..15 row within 16-row chunk
    const int scol = (lane & 3) * 8;     // 0,8,16,24

    floatx4 acc[4][4] = {};

    for (int k0 = 0; k0 < D_DIM; k0 += 32) {
        #pragma unroll
        for (int j = 0; j < 2; ++j) {
            int rbase = wave * 32 + j * 16;
            const unsigned short* ga =
                &A[(size_t)(m0 + rbase + srow) * D_DIM + k0 + scol];
            const unsigned short* gb =
                &Bt[(size_t)(n0 + rbase + srow) * D_DIM + k0 + scol];
            __builtin_amdgcn_global_load_lds(
                (const __attribute__((address_space(1))) void*)ga,
                (__attribute__((address_space(3))) void*)&As[rbase * 32],
                16, 0, 0);
            __builtin_amdgcn_global_load_lds(
                (const __attribute__((address_space(1))) void*)gb,
                (__attribute__((address_space(3))) void*)&Bs[rbase * 32],
                16, 0, 0);
        }
        __syncthreads();

        bf16x8 af[4], bfr[4];
        #pragma unroll
        for (int mi = 0; mi < 4; ++mi)
            af[mi] = *(const bf16x8*)(&As[(wm + mi * 16 + lrow) * 32 + quad * 8]);
        #pragma unroll
        for (int ni = 0; ni < 4; ++ni)
            bfr[ni] = *(const bf16x8*)(&Bs[(wn + ni * 16 + lrow) * 32 + quad * 8]);

        #pragma unroll
        for (int mi = 0; mi < 4; ++mi)
            #pragma unroll
            for (int ni = 0; ni < 4; ++ni)
                acc[mi][ni] = __builtin_amdgcn_mfma_f32_16x16x32_bf16(
                    af[mi], bfr[ni], acc[mi][ni], 0, 0, 0);
        __syncthreads();
    }

    // C store
    #pragma unroll
    for (int mi = 0; mi < 4; ++mi) {
        #pragma unroll
        for (int ni = 0; ni < 4; ++ni) {
            #pragma unroll
            for (int r = 0; r < 4; ++r) {
                int gm = m0 + wm + mi * 16 + quad * 4 + r;
                int gn = n0 + wn + ni * 16 + lrow;
                C[(size_t)gm * D_DIM + gn] = f2bf(acc[mi][ni][r]);
            }
        }
    }

    // fused logit partials
    const int h0 = (n0 + wn) >> 8;
    float asv[4], adv[4];
    #pragma unroll
    for (int ni = 0; ni < 4; ++ni) {
        int gn = n0 + wn + ni * 16 + lrow;
        asv[ni] = att_src[gn];
        adv[ni] = att_dst[gn];
    }
    #pragma unroll
    for (int mi = 0; mi < 4; ++mi) {
        #pragma unroll
        for (int r = 0; r < 4; ++r) {
            float ps = 0.f, pd = 0.f;
            #pragma unroll
            for (int ni = 0; ni < 4; ++ni) {
                ps += acc[mi][ni][r] * asv[ni];
                pd += acc[mi][ni][r] * adv[ni];
            }
            #pragma unroll
            for (int off = 8; off > 0; off >>= 1) {
                ps += __shfl_down(ps, off, 16);
                pd += __shfl_down(pd, off, 16);
            }
            if (lrow == 0) {
                int gm = m0 + wm + mi * 16 + quad * 4 + r;
                atomicAdd(&a_src[gm * 4 + h0], ps);
                atomicAdd(&a_dst[gm * 4 + h0], pd);
            }
        }
    }
}

// ---------------- degree count (incl. self loops) ---------------------------
__global__ __launch_bounds__(256) void k_deg(
        const int* __restrict__ ei, int* __restrict__ deg) {
    int e = blockIdx.x * 256 + threadIdx.x;
    if (e >= NE) return;
    int d = (e < E_EDGES) ? ei[E_EDGES + e] : (e - E_EDGES);
    atomicAdd(&deg[d], 1);
}

// ---------------- 3-phase exclusive scan of deg -> rowstart -----------------
__global__ __launch_bounds__(256) void k_scan1(
        const int* __restrict__ deg, int* __restrict__ rowstart,
        int* __restrict__ blocksum) {
    __shared__ int smem[256];
    int i = blockIdx.x * 256 + threadIdx.x;
    int v = (i < N_NODES) ? deg[i] : 0;
    smem[threadIdx.x] = v;
    __syncthreads();
    #pragma unroll
    for (int off = 1; off < 256; off <<= 1) {
        int t = (threadIdx.x >= off) ? smem[threadIdx.x - off] : 0;
        __syncthreads();
        smem[threadIdx.x] += t;
        __syncthreads();
    }
    if (i < N_NODES) rowstart[i] = smem[threadIdx.x] - v;   // local exclusive
    if (threadIdx.x == 255) blocksum[blockIdx.x] = smem[255];
}

__global__ __launch_bounds__(128) void k_scan2(
        const int* __restrict__ blocksum, int* __restrict__ blockoff) {
    __shared__ int smem[128];
    int v = (threadIdx.x < NBLK_SCAN) ? blocksum[threadIdx.x] : 0;
    smem[threadIdx.x] = v;
    __syncthreads();
    #pragma unroll
    for (int off = 1; off < 128; off <<= 1) {
        int t = (threadIdx.x >= off) ? smem[threadIdx.x - off] : 0;
        __syncthreads();
        smem[threadIdx.x] += t;
        __syncthreads();
    }
    blockoff[threadIdx.x] = smem[threadIdx.x] - v;          // exclusive
}

__global__ __launch_bounds__(256) void k_scan3(
        int* __restrict__ rowstart, const int* __restrict__ blockoff) {
    int i = blockIdx.x * 256 + threadIdx.x;
    if (i < N_NODES) rowstart[i] += blockoff[blockIdx.x];
    if (i == 0) rowstart[N_NODES] = NE;
}

// ---------------- edge exp + scatter into CSR slots -------------------------
__global__ __launch_bounds__(256) void k_edge_exp_scatter(
        const int* __restrict__ ei,
        const float* __restrict__ a_src, const float* __restrict__ a_dst,
        const int* __restrict__ rowstart, int* __restrict__ cursor,
        int* __restrict__ csr_src, float* __restrict__ csr_ee) {
    int e = blockIdx.x * 256 + threadIdx.x;
    if (e >= NE) return;
    int s, d;
    if (e < E_EDGES) { s = ei[e]; d = ei[E_EDGES + e]; }
    else             { s = d = e - E_EDGES; }
    float4 as = *(const float4*)(&a_src[s * 4]);
    float4 ad = *(const float4*)(&a_dst[d * 4]);
    float l0 = as.x + ad.x, l1 = as.y + ad.y, l2 = as.z + ad.z, l3 = as.w + ad.w;
    l0 = l0 > 0.f ? l0 : NEG_SLOPE * l0;
    l1 = l1 > 0.f ? l1 : NEG_SLOPE * l1;
    l2 = l2 > 0.f ? l2 : NEG_SLOPE * l2;
    l3 = l3 > 0.f ? l3 : NEG_SLOPE * l3;
    int pos  = atomicAdd(&cursor[d], 1);
    int slot = rowstart[d] + pos;
    csr_src[slot] = s;
    *(float4*)(&csr_ee[(size_t)slot * 4]) =
        make_float4(__expf(l0), __expf(l1), __expf(l2), __expf(l3));
}

// ---------------- per-node aggregation: one wave per node -------------------
// 64 lanes x 16 channels; head h = lane>>4, c = h*256 + (lane&15)*16.
// No LDS/barrier; z via in-wave butterfly. NT hints on streams so xp stays
// cache-resident (round-3 showed 405 MB HBM refetch of a 51 MB working set).
__device__ __forceinline__ void acc16(float* acc, float a,
                                      ushort8 v0, ushort8 v1) {
    #pragma unroll
    for (int j = 0; j < 8; ++j) acc[j]     += a * bf2f((unsigned short)v0[j]);
    #pragma unroll
    for (int j = 0; j < 8; ++j) acc[8 + j] += a * bf2f((unsigned short)v1[j]);
}

__global__ __launch_bounds__(256) void k_node_aggregate(
        const int* __restrict__ csr_src, const float* __restrict__ csr_ee,
        const int* __restrict__ rowstart,
        const unsigned short* __restrict__ xp,
        const float* __restrict__ bias, float* __restrict__ out) {
    const int tid  = threadIdx.x;
    const int lane = tid & 63;
    const int n    = blockIdx.x * 4 + (tid >> 6);   // 6250*4 = 25000 exact
    const int row  = rowstart[n];
    const int deg  = rowstart[n + 1] - row;

    // z: in-wave butterfly reduction of csr_ee rows
    float z0 = 0.f, z1 = 0.f, z2 = 0.f, z3 = 0.f;
    for (int i = lane; i < deg; i += 64) {
        f32x4v v = __builtin_nontemporal_load((const f32x4v*)csr_ee + (row + i));
        z0 += v.x; z1 += v.y; z2 += v.z; z3 += v.w;
    }
    #pragma unroll
    for (int off = 32; off > 0; off >>= 1) {
        z0 += __shfl_xor(z0, off);
        z1 += __shfl_xor(z1, off);
        z2 += __shfl_xor(z2, off);
        z3 += __shfl_xor(z3, off);
    }
    const int h = lane >> 4;
    float zh = (h == 0) ? z0 : (h == 1) ? z1 : (h == 2) ? z2 : z3;
    const float rz = 1.0f / zh;

    const int c = h * 256 + (lane & 15) * 16;

    float acc[16] = {};
    int i = 0;
    for (; i + 4 <= deg; i += 4) {
        int s0 = __builtin_nontemporal_load(&csr_src[row + i + 0]);
        int s1 = __builtin_nontemporal_load(&csr_src[row + i + 1]);
        int s2 = __builtin_nontemporal_load(&csr_src[row + i + 2]);
        int s3 = __builtin_nontemporal_load(&csr_src[row + i + 3]);
        float a0 = __builtin_nontemporal_load(&csr_ee[(size_t)(row+i+0)*4+h]) * rz;
        float a1 = __builtin_nontemporal_load(&csr_ee[(size_t)(row+i+1)*4+h]) * rz;
        float a2 = __builtin_nontemporal_load(&csr_ee[(size_t)(row+i+2)*4+h]) * rz;
        float a3 = __builtin_nontemporal_load(&csr_ee[(size_t)(row+i+3)*4+h]) * rz;
        ushort8 v00 = *(const ushort8*)(&xp[(size_t)s0 * D_DIM + c]);
        ushort8 v01 = *(const ushort8*)(&xp[(size_t)s0 * D_DIM + c + 8]);
        ushort8 v10 = *(const ushort8*)(&xp[(size_t)s1 * D_DIM + c]);
        ushort8 v11 = *(const ushort8*)(&xp[(size_t)s1 * D_DIM + c + 8]);
        ushort8 v20 = *(const ushort8*)(&xp[(size_t)s2 * D_DIM + c]);
        ushort8 v21 = *(const ushort8*)(&xp[(size_t)s2 * D_DIM + c + 8]);
        ushort8 v30 = *(const ushort8*)(&xp[(size_t)s3 * D_DIM + c]);
        ushort8 v31 = *(const ushort8*)(&xp[(size_t)s3 * D_DIM + c + 8]);
        acc16(acc, a0, v00, v01);
        acc16(acc, a1, v10, v11);
        acc16(acc, a2, v20, v21);
        acc16(acc, a3, v30, v31);
    }
    for (; i < deg; ++i) {
        int s   = __builtin_nontemporal_load(&csr_src[row + i]);
        float a = __builtin_nontemporal_load(&csr_ee[(size_t)(row+i)*4+h]) * rz;
        ushort8 v0 = *(const ushort8*)(&xp[(size_t)s * D_DIM + c]);
        ushort8 v1 = *(const ushort8*)(&xp[(size_t)s * D_DIM + c + 8]);
        acc16(acc, a, v0, v1);
    }

    #pragma unroll
    for (int q = 0; q < 4; ++q) {
        float4 b = *(const float4*)(&bias[c + q * 4]);
        f32x4v o;
        o.x = fmaxf(acc[q * 4 + 0] + b.x, 0.f);
        o.y = fmaxf(acc[q * 4 + 1] + b.y, 0.f);
        o.z = fmaxf(acc[q * 4 + 2] + b.z, 0.f);
        o.w = fmaxf(acc[q * 4 + 3] + b.w, 0.f);
        __builtin_nontemporal_store(o, (f32x4v*)&out[(size_t)n * D_DIM + c + q * 4]);
    }
}

extern "C" void kernel_launch(void* const* d_in, const int* in_sizes, int n_in,
                              void* d_out, int out_size, void* d_ws, size_t ws_size,
                              hipStream_t stream) {
    const float* x       = (const float*)d_in[0];
    const int*   ei      = (const int*)d_in[1];      // [2][E] int32
    const float* W       = (const float*)d_in[2];
    const float* att_src = (const float*)d_in[3];
    const float* att_dst = (const float*)d_in[4];
    const float* bias    = (const float*)d_in[5];
    float* out = (float*)d_out;

    char* ws = (char*)d_ws;
    size_t off = 0;
    auto alloc = [&](size_t bytes) -> void* {
        void* p = ws + off;
        off = (off + bytes + 255) & ~(size_t)255;
        return p;
    };
    unsigned short* xb   = (unsigned short*)alloc((size_t)M_PAD * D_DIM * 2);
    unsigned short* Wt   = (unsigned short*)alloc((size_t)D_DIM * D_DIM * 2);
    unsigned short* xpb  = (unsigned short*)alloc((size_t)M_PAD * D_DIM * 2);
    float* a_src    = (float*)alloc((size_t)M_PAD * 4 * 4);   // padded rows ok
    float* a_dst    = (float*)alloc((size_t)M_PAD * 4 * 4);
    int*   deg      = (int*)alloc((size_t)N_NODES * 4);
    int*   rowstart = (int*)alloc((size_t)(N_NODES + 1) * 4);
    int*   cursor   = (int*)alloc((size_t)N_NODES * 4);
    int*   blocksum = (int*)alloc((size_t)NBLK_SCAN * 4);
    int*   blockoff = (int*)alloc((size_t)128 * 4);
    int*   csr_src  = (int*)alloc((size_t)NE * 4);
    float* csr_ee   = (float*)alloc((size_t)NE * 4 * 4);

    hipMemsetAsync(deg, 0, (size_t)N_NODES * 4, stream);
    hipMemsetAsync(cursor, 0, (size_t)N_NODES * 4, stream);
    hipMemsetAsync(a_src, 0, (size_t)M_PAD * 4 * 4, stream);
    hipMemsetAsync(a_dst, 0, (size_t)M_PAD * 4 * 4, stream);

    k_convert_x<<<M_PAD, 256, 0, stream>>>(x, xb);
    k_convert_wt<<<dim3(32, 32), dim3(32, 8), 0, stream>>>(W, Wt);
    k_gemm<<<dim3(M_PAD / 128, D_DIM / 128), 256, 0, stream>>>(
        xb, Wt, xpb, att_src, att_dst, a_src, a_dst);
    k_deg<<<(NE + 255) / 256, 256, 0, stream>>>(ei, deg);
    k_scan1<<<NBLK_SCAN, 256, 0, stream>>>(deg, rowstart, blocksum);
    k_scan2<<<1, 128, 0, stream>>>(blocksum, blockoff);
    k_scan3<<<NBLK_SCAN, 256, 0, stream>>>(rowstart, blockoff);
    k_edge_exp_scatter<<<(NE + 255) / 256, 256, 0, stream>>>(
        ei, a_src, a_dst, rowstart, cursor, csr_src, csr_ee);
    k_node_aggregate<<<6250, 256, 0, stream>>>(
        csr_src, csr_ee, rowstart, xpb, bias, out);
}

// Round 5
// 481.157 us; speedup vs baseline: 1.0755x; 1.0755x over previous
//
#include <hip/hip_runtime.h>
#include <hip/hip_bf16.h>
#include <stdint.h>

#define N_NODES 25000
#define M_PAD   25088          // 196 * 128
#define E_EDGES 400000
#define NE      (E_EDGES + N_NODES)   // 425000 (edges + self loops)
#define HEADS   4
#define D_DIM   1024           // H*C = D_IN = 1024
#define NEG_SLOPE 0.2f
#define NBLK_SCAN ((N_NODES + 255) / 256)   // 98
#define CHUNKS  16             // 64-channel chunks; slice = M_PAD*64*2B = 3.2MB
#define GRP     1563           // ceil(25000/16) node-groups per chunk

using bf16x8  = __attribute__((ext_vector_type(8))) short;
using floatx4 = __attribute__((ext_vector_type(4))) float;
using ushort8 = __attribute__((ext_vector_type(8))) unsigned short;

__device__ __forceinline__ unsigned short f2bf(float f) {
    union { float f; unsigned u; } v{f};
    unsigned r = v.u + 0x7fffu + ((v.u >> 16) & 1u);   // round-to-nearest-even
    return (unsigned short)(r >> 16);
}
__device__ __forceinline__ float bf2f(unsigned short s) {
    union { unsigned u; float f; } v{(unsigned)s << 16};
    return v.f;
}

// ---------------- convert x (fp32 -> bf16, zero-pad rows to M_PAD) ----------
__global__ __launch_bounds__(256) void k_convert_x(
        const float* __restrict__ x, unsigned short* __restrict__ xb) {
    int i = blockIdx.x * 256 + threadIdx.x;          // quad index
    int row = i >> 8;                                // 256 quads per row
    if (row >= M_PAD) return;
    ushort4 o;
    if (row < N_NODES) {
        float4 v = ((const float4*)x)[i];
        o = make_ushort4(f2bf(v.x), f2bf(v.y), f2bf(v.z), f2bf(v.w));
    } else {
        o = make_ushort4(0, 0, 0, 0);
    }
    ((ushort4*)xb)[i] = o;
}

// ---------------- convert W (fp32 [K][N] -> bf16 transposed [N][K]) ---------
__global__ void k_convert_wt(const float* __restrict__ W,
                             unsigned short* __restrict__ Wt) {
    __shared__ float tile[32][33];
    int bx = blockIdx.x, by = blockIdx.y;
    int tx = threadIdx.x, ty = threadIdx.y;          // 32 x 8
    #pragma unroll
    for (int i = 0; i < 32; i += 8) {
        int k = by * 32 + ty + i;
        int n = bx * 32 + tx;
        tile[ty + i][tx] = W[(size_t)k * D_DIM + n];
    }
    __syncthreads();
    #pragma unroll
    for (int i = 0; i < 32; i += 8) {
        int n = bx * 32 + ty + i;
        int k = by * 32 + tx;
        Wt[(size_t)n * D_DIM + k] = f2bf(tile[tx][ty + i]);
    }
}

// ---------------- GEMM: xp = x @ W  (output in chunked layout) --------------
// bf16 MFMA 128x128 tile, BK=32, global_load_lds staging.
// C store: xp_t[chunk][node][64] with chunk = gn>>6 — sets up L2-resident
// slices for the chunked aggregation.
__global__ __launch_bounds__(256) void k_gemm(
        const unsigned short* __restrict__ A,
        const unsigned short* __restrict__ Bt,
        unsigned short* __restrict__ C) {
    __shared__ __align__(16) unsigned short As[128 * 32];
    __shared__ __align__(16) unsigned short Bs[128 * 32];

    const int tid  = threadIdx.x;
    const int m0   = blockIdx.x * 128;
    const int n0   = blockIdx.y * 128;
    const int wave = tid >> 6, lane = tid & 63;
    const int wm   = (wave & 1) * 64, wn = (wave >> 1) * 64;
    const int lrow = lane & 15;
    const int quad = lane >> 4;

    const int srow = (lane >> 2);        // 0..15 row within 16-row chunk
    const int scol = (lane & 3) * 8;     // 0,8,16,24

    floatx4 acc[4][4] = {};

    for (int k0 = 0; k0 < D_DIM; k0 += 32) {
        #pragma unroll
        for (int j = 0; j < 2; ++j) {
            int rbase = wave * 32 + j * 16;
            const unsigned short* ga =
                &A[(size_t)(m0 + rbase + srow) * D_DIM + k0 + scol];
            const unsigned short* gb =
                &Bt[(size_t)(n0 + rbase + srow) * D_DIM + k0 + scol];
            __builtin_amdgcn_global_load_lds(
                (const __attribute__((address_space(1))) void*)ga,
                (__attribute__((address_space(3))) void*)&As[rbase * 32],
                16, 0, 0);
            __builtin_amdgcn_global_load_lds(
                (const __attribute__((address_space(1))) void*)gb,
                (__attribute__((address_space(3))) void*)&Bs[rbase * 32],
                16, 0, 0);
        }
        __syncthreads();

        bf16x8 af[4], bfr[4];
        #pragma unroll
        for (int mi = 0; mi < 4; ++mi)
            af[mi] = *(const bf16x8*)(&As[(wm + mi * 16 + lrow) * 32 + quad * 8]);
        #pragma unroll
        for (int ni = 0; ni < 4; ++ni)
            bfr[ni] = *(const bf16x8*)(&Bs[(wn + ni * 16 + lrow) * 32 + quad * 8]);

        #pragma unroll
        for (int mi = 0; mi < 4; ++mi)
            #pragma unroll
            for (int ni = 0; ni < 4; ++ni)
                acc[mi][ni] = __builtin_amdgcn_mfma_f32_16x16x32_bf16(
                    af[mi], bfr[ni], acc[mi][ni], 0, 0, 0);
        __syncthreads();
    }

    #pragma unroll
    for (int mi = 0; mi < 4; ++mi) {
        #pragma unroll
        for (int ni = 0; ni < 4; ++ni) {
            #pragma unroll
            for (int r = 0; r < 4; ++r) {
                int gm = m0 + wm + mi * 16 + quad * 4 + r;
                int gn = n0 + wn + ni * 16 + lrow;
                int ch = gn >> 6, sub = gn & 63;
                C[((size_t)ch * M_PAD + gm) * 64 + sub] = f2bf(acc[mi][ni][r]);
            }
        }
    }
}

// ---------------- per-node attention logits a_src/a_dst [N][H] --------------
__global__ __launch_bounds__(256) void k_node_logits(
        const unsigned short* __restrict__ xp_t,
        const float* __restrict__ att_src, const float* __restrict__ att_dst,
        float* __restrict__ a_src, float* __restrict__ a_dst) {
    int n = blockIdx.x;
    int tid = threadIdx.x;
    int h = tid >> 6, lane = tid & 63;
    int c = h * 256 + lane * 4;
    int ch = c >> 6, sub = c & 63;
    ushort4 v  = *(const ushort4*)(&xp_t[((size_t)ch * M_PAD + n) * 64 + sub]);
    float4 as  = *(const float4*)(&att_src[c]);
    float4 ad  = *(const float4*)(&att_dst[c]);
    float x0 = bf2f(v.x), x1 = bf2f(v.y), x2 = bf2f(v.z), x3 = bf2f(v.w);
    float s = x0 * as.x + x1 * as.y + x2 * as.z + x3 * as.w;
    float d = x0 * ad.x + x1 * ad.y + x2 * ad.z + x3 * ad.w;
    #pragma unroll
    for (int off = 32; off > 0; off >>= 1) {
        s += __shfl_down(s, off);
        d += __shfl_down(d, off);
    }
    if (lane == 0) { a_src[n * 4 + h] = s; a_dst[n * 4 + h] = d; }
}

// ---------------- degree count (incl. self loops) ---------------------------
__global__ __launch_bounds__(256) void k_deg(
        const int* __restrict__ ei, int* __restrict__ deg) {
    int e = blockIdx.x * 256 + threadIdx.x;
    if (e >= NE) return;
    int d = (e < E_EDGES) ? ei[E_EDGES + e] : (e - E_EDGES);
    atomicAdd(&deg[d], 1);
}

// ---------------- 3-phase exclusive scan of deg -> rowstart -----------------
__global__ __launch_bounds__(256) void k_scan1(
        const int* __restrict__ deg, int* __restrict__ rowstart,
        int* __restrict__ blocksum) {
    __shared__ int smem[256];
    int i = blockIdx.x * 256 + threadIdx.x;
    int v = (i < N_NODES) ? deg[i] : 0;
    smem[threadIdx.x] = v;
    __syncthreads();
    #pragma unroll
    for (int off = 1; off < 256; off <<= 1) {
        int t = (threadIdx.x >= off) ? smem[threadIdx.x - off] : 0;
        __syncthreads();
        smem[threadIdx.x] += t;
        __syncthreads();
    }
    if (i < N_NODES) rowstart[i] = smem[threadIdx.x] - v;   // local exclusive
    if (threadIdx.x == 255) blocksum[blockIdx.x] = smem[255];
}

__global__ __launch_bounds__(128) void k_scan2(
        const int* __restrict__ blocksum, int* __restrict__ blockoff) {
    __shared__ int smem[128];
    int v = (threadIdx.x < NBLK_SCAN) ? blocksum[threadIdx.x] : 0;
    smem[threadIdx.x] = v;
    __syncthreads();
    #pragma unroll
    for (int off = 1; off < 128; off <<= 1) {
        int t = (threadIdx.x >= off) ? smem[threadIdx.x - off] : 0;
        __syncthreads();
        smem[threadIdx.x] += t;
        __syncthreads();
    }
    blockoff[threadIdx.x] = smem[threadIdx.x] - v;          // exclusive
}

__global__ __launch_bounds__(256) void k_scan3(
        int* __restrict__ rowstart, const int* __restrict__ blockoff) {
    int i = blockIdx.x * 256 + threadIdx.x;
    if (i < N_NODES) rowstart[i] += blockoff[blockIdx.x];
    if (i == 0) rowstart[N_NODES] = NE;
}

// ---------------- edge exp + scatter into CSR slots -------------------------
__global__ __launch_bounds__(256) void k_edge_exp_scatter(
        const int* __restrict__ ei,
        const float* __restrict__ a_src, const float* __restrict__ a_dst,
        const int* __restrict__ rowstart, int* __restrict__ cursor,
        int* __restrict__ csr_src, float* __restrict__ csr_ee) {
    int e = blockIdx.x * 256 + threadIdx.x;
    if (e >= NE) return;
    int s, d;
    if (e < E_EDGES) { s = ei[e]; d = ei[E_EDGES + e]; }
    else             { s = d = e - E_EDGES; }
    float4 as = *(const float4*)(&a_src[s * 4]);
    float4 ad = *(const float4*)(&a_dst[d * 4]);
    float l0 = as.x + ad.x, l1 = as.y + ad.y, l2 = as.z + ad.z, l3 = as.w + ad.w;
    l0 = l0 > 0.f ? l0 : NEG_SLOPE * l0;
    l1 = l1 > 0.f ? l1 : NEG_SLOPE * l1;
    l2 = l2 > 0.f ? l2 : NEG_SLOPE * l2;
    l3 = l3 > 0.f ? l3 : NEG_SLOPE * l3;
    int pos  = atomicAdd(&cursor[d], 1);
    int slot = rowstart[d] + pos;
    csr_src[slot] = s;
    *(float4*)(&csr_ee[(size_t)slot * 4]) =
        make_float4(__expf(l0), __expf(l1), __expf(l2), __expf(l3));
}

// ---------------- normalize: alpha[h][slot] = ee/z (head-planar) ------------
__global__ __launch_bounds__(256) void k_alpha(
        const float* __restrict__ csr_ee, const int* __restrict__ rowstart,
        float* __restrict__ alpha) {
    const int lane = threadIdx.x & 63;
    const int n    = blockIdx.x * 4 + (threadIdx.x >> 6);   // 6250*4 = 25000
    const int row  = rowstart[n];
    const int deg  = rowstart[n + 1] - row;

    float z0 = 0.f, z1 = 0.f, z2 = 0.f, z3 = 0.f;
    for (int i = lane; i < deg; i += 64) {
        float4 v = *(const float4*)(&csr_ee[(size_t)(row + i) * 4]);
        z0 += v.x; z1 += v.y; z2 += v.z; z3 += v.w;
    }
    #pragma unroll
    for (int off = 32; off > 0; off >>= 1) {
        z0 += __shfl_xor(z0, off);
        z1 += __shfl_xor(z1, off);
        z2 += __shfl_xor(z2, off);
        z3 += __shfl_xor(z3, off);
    }
    float r0 = 1.f / z0, r1 = 1.f / z1, r2 = 1.f / z2, r3 = 1.f / z3;
    for (int i = lane; i < deg; i += 64) {
        float4 v = *(const float4*)(&csr_ee[(size_t)(row + i) * 4]);
        alpha[0 * (size_t)NE + row + i] = v.x * r0;
        alpha[1 * (size_t)NE + row + i] = v.y * r1;
        alpha[2 * (size_t)NE + row + i] = v.z * r2;
        alpha[3 * (size_t)NE + row + i] = v.w * r3;
    }
}

// ---------------- chunked per-node aggregation ------------------------------
// 16 chunks of 64 channels; slice xp_t[chunk] = 3.2 MB fits one XCD's 4 MiB
// L2. XCD swizzle: block b -> XCD b&7 (dispatch heuristic); XCD k handles
// chunks 2k,2k+1 so its L2 holds one slice at a time. Block = 16 nodes x
// (16 threads x 4ch). No LDS, no barriers.
__global__ __launch_bounds__(256) void k_node_aggregate(
        const int* __restrict__ csr_src, const float* __restrict__ alpha,
        const int* __restrict__ rowstart,
        const unsigned short* __restrict__ xp_t,
        const float* __restrict__ bias, float* __restrict__ out) {
    const int b    = blockIdx.x;
    const int xcd  = b & 7;
    const int seq  = b >> 3;                  // 0 .. 2*GRP-1
    const int hi   = (seq >= GRP) ? 1 : 0;
    const int ch   = xcd * 2 + hi;            // chunk 0..15
    const int grp  = seq - hi * GRP;

    const int t    = threadIdx.x;
    const int slot = t >> 4;                  // node within block (0..15)
    const int sub4 = (t & 15) * 4;            // channel*4 within chunk
    const int n    = grp * 16 + slot;
    if (n >= N_NODES) return;

    const int h   = ch >> 2;
    const int row = rowstart[n];
    const int deg = rowstart[n + 1] - row;

    const float* __restrict__ alpha_h = alpha + (size_t)h * NE;
    const unsigned short* __restrict__ base =
        xp_t + (size_t)ch * M_PAD * 64 + sub4;

    float a0 = 0.f, a1 = 0.f, a2 = 0.f, a3 = 0.f;
    int i = 0;
    for (; i + 2 <= deg; i += 2) {
        int   s0 = csr_src[row + i];
        int   s1 = csr_src[row + i + 1];
        float w0 = alpha_h[row + i];
        float w1 = alpha_h[row + i + 1];
        ushort4 v0 = *(const ushort4*)(base + (size_t)s0 * 64);
        ushort4 v1 = *(const ushort4*)(base + (size_t)s1 * 64);
        a0 += w0 * bf2f(v0.x) + w1 * bf2f(v1.x);
        a1 += w0 * bf2f(v0.y) + w1 * bf2f(v1.y);
        a2 += w0 * bf2f(v0.z) + w1 * bf2f(v1.z);
        a3 += w0 * bf2f(v0.w) + w1 * bf2f(v1.w);
    }
    if (i < deg) {
        int   s0 = csr_src[row + i];
        float w0 = alpha_h[row + i];
        ushort4 v0 = *(const ushort4*)(base + (size_t)s0 * 64);
        a0 += w0 * bf2f(v0.x);
        a1 += w0 * bf2f(v0.y);
        a2 += w0 * bf2f(v0.z);
        a3 += w0 * bf2f(v0.w);
    }

    const int c = ch * 64 + sub4;
    float4 bv = *(const float4*)(&bias[c]);
    float4 o;
    o.x = fmaxf(a0 + bv.x, 0.f);
    o.y = fmaxf(a1 + bv.y, 0.f);
    o.z = fmaxf(a2 + bv.z, 0.f);
    o.w = fmaxf(a3 + bv.w, 0.f);
    *(float4*)(&out[(size_t)n * D_DIM + c]) = o;
}

extern "C" void kernel_launch(void* const* d_in, const int* in_sizes, int n_in,
                              void* d_out, int out_size, void* d_ws, size_t ws_size,
                              hipStream_t stream) {
    const float* x       = (const float*)d_in[0];
    const int*   ei      = (const int*)d_in[1];      // [2][E] int32
    const float* W       = (const float*)d_in[2];
    const float* att_src = (const float*)d_in[3];
    const float* att_dst = (const float*)d_in[4];
    const float* bias    = (const float*)d_in[5];
    float* out = (float*)d_out;

    char* ws = (char*)d_ws;
    size_t off = 0;
    auto alloc = [&](size_t bytes) -> void* {
        void* p = ws + off;
        off = (off + bytes + 255) & ~(size_t)255;
        return p;
    };
    unsigned short* xb   = (unsigned short*)alloc((size_t)M_PAD * D_DIM * 2);
    unsigned short* Wt   = (unsigned short*)alloc((size_t)D_DIM * D_DIM * 2);
    unsigned short* xpt  = (unsigned short*)alloc((size_t)M_PAD * D_DIM * 2);
    float* a_src    = (float*)alloc((size_t)N_NODES * 4 * 4);
    float* a_dst    = (float*)alloc((size_t)N_NODES * 4 * 4);
    int*   deg      = (int*)alloc((size_t)N_NODES * 4);       // deg+cursor
    int*   cursor   = (int*)alloc((size_t)N_NODES * 4);       //  contiguous
    int*   rowstart = (int*)alloc((size_t)(N_NODES + 1) * 4);
    int*   blocksum = (int*)alloc((size_t)NBLK_SCAN * 4);
    int*   blockoff = (int*)alloc((size_t)128 * 4);
    int*   csr_src  = (int*)alloc((size_t)NE * 4);
    float* csr_ee   = (float*)alloc((size_t)NE * 4 * 4);
    float* alpha    = (float*)alloc((size_t)NE * 4 * 4);

    // single memset covers deg + (alignment pad) + cursor
    size_t degspan = (size_t)((char*)cursor - (char*)deg) + (size_t)N_NODES * 4;
    hipMemsetAsync(deg, 0, degspan, stream);

    k_convert_x<<<M_PAD, 256, 0, stream>>>(x, xb);
    k_convert_wt<<<dim3(32, 32), dim3(32, 8), 0, stream>>>(W, Wt);
    k_gemm<<<dim3(M_PAD / 128, D_DIM / 128), 256, 0, stream>>>(xb, Wt, xpt);
    k_node_logits<<<N_NODES, 256, 0, stream>>>(xpt, att_src, att_dst, a_src, a_dst);
    k_deg<<<(NE + 255) / 256, 256, 0, stream>>>(ei, deg);
    k_scan1<<<NBLK_SCAN, 256, 0, stream>>>(deg, rowstart, blocksum);
    k_scan2<<<1, 128, 0, stream>>>(blocksum, blockoff);
    k_scan3<<<NBLK_SCAN, 256, 0, stream>>>(rowstart, blockoff);
    k_edge_exp_scatter<<<(NE + 255) / 256, 256, 0, stream>>>(
        ei, a_src, a_dst, rowstart, cursor, csr_src, csr_ee);
    k_alpha<<<6250, 256, 0, stream>>>(csr_ee, rowstart, alpha);
    k_node_aggregate<<<CHUNKS * GRP, 256, 0, stream>>>(
        csr_src, alpha, rowstart, xpt, bias, out);
}